// Round 2
// baseline (701.573 us; speedup 1.0000x reference)
//
#include <hip/hip_runtime.h>
#include <math.h>

#define HIDDEN 2048
#define N_EXPERTS 5
#define TOP_K 2

// Native clang vector type — __builtin_nontemporal_* requires a real vector type,
// not HIP's HIP_vector_type<float,4> class.
typedef float vfloat4 __attribute__((ext_vector_type(4)));

// Wave-per-token MoE gate + fused token copy.
// block = 512 (8 waves), __launch_bounds__(512, 8) -> 4 blocks/CU (160 KB LDS = full
// pool), 32 waves/CU = 100% occupancy (was 16 waves/CU = 46%).
// Non-temporal load/store for the streamed token copy kill the TCC write-allocate
// fetch (was re-fetching all 268 MB of out_tok before overwriting it).
__global__ __launch_bounds__(512, 8)
void moe_gate_kernel(const float* __restrict__ x,      // [N, HIDDEN]
                     const float* __restrict__ W,      // [N_EXPERTS, HIDDEN]
                     float* __restrict__ out_w,        // [N, 2]
                     float* __restrict__ out_i,        // [N, 2] (indices as floats)
                     float* __restrict__ out_tok,      // [N, HIDDEN]
                     int n_tokens) {
    __shared__ float w_lds[N_EXPERTS * HIDDEN];  // 40 KB

    // Cooperative W load: 10240 floats = 2560 float4
    {
        const vfloat4* Wv = (const vfloat4*)W;
        vfloat4* Lv = (vfloat4*)w_lds;
        for (int i = threadIdx.x; i < (N_EXPERTS * HIDDEN) / 4; i += blockDim.x) {
            Lv[i] = Wv[i];
        }
    }
    __syncthreads();

    const int lane = threadIdx.x & 63;
    const int wave = threadIdx.x >> 6;
    const int waves_per_block = blockDim.x >> 6;
    const int global_wave = blockIdx.x * waves_per_block + wave;
    const int total_waves = gridDim.x * waves_per_block;

    const vfloat4* w_lds_v = (const vfloat4*)w_lds;

    for (int tok = global_wave; tok < n_tokens; tok += total_waves) {
        const vfloat4* xp = (const vfloat4*)(x + (size_t)tok * HIDDEN);
        vfloat4* op = (vfloat4*)(out_tok + (size_t)tok * HIDDEN);

        float acc0 = 0.f, acc1 = 0.f, acc2 = 0.f, acc3 = 0.f, acc4 = 0.f;

        #pragma unroll
        for (int j = 0; j < HIDDEN / 4 / 64; ++j) {   // 8 iterations
            const int idx = j * 64 + lane;            // float4 index, coalesced
            const vfloat4 xv = __builtin_nontemporal_load(&xp[idx]);
            __builtin_nontemporal_store(xv, &op[idx]);  // fused tokens copy, no L2 alloc
            {
                const vfloat4 wv = w_lds_v[0 * (HIDDEN / 4) + idx];
                acc0 += xv.x * wv.x + xv.y * wv.y + xv.z * wv.z + xv.w * wv.w;
            }
            {
                const vfloat4 wv = w_lds_v[1 * (HIDDEN / 4) + idx];
                acc1 += xv.x * wv.x + xv.y * wv.y + xv.z * wv.z + xv.w * wv.w;
            }
            {
                const vfloat4 wv = w_lds_v[2 * (HIDDEN / 4) + idx];
                acc2 += xv.x * wv.x + xv.y * wv.y + xv.z * wv.z + xv.w * wv.w;
            }
            {
                const vfloat4 wv = w_lds_v[3 * (HIDDEN / 4) + idx];
                acc3 += xv.x * wv.x + xv.y * wv.y + xv.z * wv.z + xv.w * wv.w;
            }
            {
                const vfloat4 wv = w_lds_v[4 * (HIDDEN / 4) + idx];
                acc4 += xv.x * wv.x + xv.y * wv.y + xv.z * wv.z + xv.w * wv.w;
            }
        }

        // Wave-wide butterfly reduction (64 lanes) for each expert logit
        float logits[N_EXPERTS] = {acc0, acc1, acc2, acc3, acc4};
        #pragma unroll
        for (int e = 0; e < N_EXPERTS; ++e) {
            float v = logits[e];
            #pragma unroll
            for (int off = 32; off > 0; off >>= 1) {
                v += __shfl_xor(v, off, 64);
            }
            logits[e] = v;
        }

        if (lane == 0) {
            // top-1: strict > keeps lowest index on ties (lax.top_k stable order)
            int i1 = 0;
            float m1 = logits[0];
            #pragma unroll
            for (int e = 1; e < N_EXPERTS; ++e) {
                if (logits[e] > m1) { m1 = logits[e]; i1 = e; }
            }
            // top-2: first (lowest-index) max among the rest
            int i2 = -1;
            float m2 = -INFINITY;
            #pragma unroll
            for (int e = 0; e < N_EXPERTS; ++e) {
                if (e != i1 && logits[e] > m2) { m2 = logits[e]; i2 = e; }
            }
            // normalized top-2 softmax weights: full softmax denom cancels
            const float r = expf(m2 - m1);          // <= 1
            const float inv = 1.0f / (1.0f + r);
            out_w[(size_t)tok * 2 + 0] = inv;
            out_w[(size_t)tok * 2 + 1] = r * inv;
            out_i[(size_t)tok * 2 + 0] = (float)i1;
            out_i[(size_t)tok * 2 + 1] = (float)i2;
        }
    }
}

extern "C" void kernel_launch(void* const* d_in, const int* in_sizes, int n_in,
                              void* d_out, int out_size, void* d_ws, size_t ws_size,
                              hipStream_t stream) {
    const float* x = (const float*)d_in[0];   // [8,4096,2048] fp32
    const float* W = (const float*)d_in[1];   // [5,2048] fp32

    const int n_tokens = in_sizes[0] / HIDDEN;              // 32768

    float* out = (float*)d_out;
    float* out_w   = out;                                    // [N,2]
    float* out_i   = out + (size_t)n_tokens * TOP_K;         // [N,2]
    float* out_tok = out + (size_t)n_tokens * TOP_K * 2;     // [N,HIDDEN]

    // 1024 blocks x 8 waves = 8192 waves -> 4 tokens per wave (grid-stride)
    dim3 grid(1024);
    dim3 block(512);
    moe_gate_kernel<<<grid, block, 0, stream>>>(x, W, out_w, out_i, out_tok, n_tokens);
}

// Round 3
// 609.137 us; speedup vs baseline: 1.1517x; 1.1517x over previous
//
#include <hip/hip_runtime.h>
#include <math.h>

#define HIDDEN 2048
#define N_EXPERTS 5
#define TOP_K 2

typedef float vfloat4 __attribute__((ext_vector_type(4)));

// Gate-only kernel: wave handles TWO consecutive tokens (shares each LDS W-read
// across both, doubles per-wave load MLP). The 268 MB token copy is done by
// hipMemcpyAsync (ROCm blit path ~6.3 TB/s, no write-allocate RMW pathology that
// capped the fused kernel at 3.5 TB/s).
// block = 256 (4 waves), 4 blocks/CU (LDS 40KB x 4 = full 160KB pool).
__global__ __launch_bounds__(256, 4)
void moe_gate_kernel(const float* __restrict__ x,      // [N, HIDDEN]
                     const float* __restrict__ W,      // [N_EXPERTS, HIDDEN]
                     float* __restrict__ out_w,        // [N, 2]
                     float* __restrict__ out_i,        // [N, 2] (indices as floats)
                     int n_tokens) {
    __shared__ float w_lds[N_EXPERTS * HIDDEN];  // 40 KB

    // Cooperative W load: 10240 floats = 2560 float4
    {
        const vfloat4* Wv = (const vfloat4*)W;
        vfloat4* Lv = (vfloat4*)w_lds;
        for (int i = threadIdx.x; i < (N_EXPERTS * HIDDEN) / 4; i += blockDim.x) {
            Lv[i] = Wv[i];
        }
    }
    __syncthreads();

    const int lane = threadIdx.x & 63;
    const int wave = threadIdx.x >> 6;
    const int waves_per_block = blockDim.x >> 6;
    const int global_wave = blockIdx.x * waves_per_block + wave;
    const int total_waves = gridDim.x * waves_per_block;

    const vfloat4* w_lds_v = (const vfloat4*)w_lds;

    const int n_pairs = (n_tokens + 1) >> 1;

    for (int p = global_wave; p < n_pairs; p += total_waves) {
        const int tokA = 2 * p;
        const int tokB = tokA + 1;
        const bool hasB = (tokB < n_tokens);
        const int tokBc = hasB ? tokB : tokA;   // duplicate A when odd tail

        const vfloat4* xa = (const vfloat4*)(x + (size_t)tokA * HIDDEN);
        const vfloat4* xb = (const vfloat4*)(x + (size_t)tokBc * HIDDEN);

        float accA[N_EXPERTS] = {0.f, 0.f, 0.f, 0.f, 0.f};
        float accB[N_EXPERTS] = {0.f, 0.f, 0.f, 0.f, 0.f};

        #pragma unroll
        for (int j = 0; j < HIDDEN / 4 / 64; ++j) {   // 8 iterations
            const int idx = j * 64 + lane;            // float4 index, coalesced
            const vfloat4 va = xa[idx];
            const vfloat4 vb = xb[idx];
            #pragma unroll
            for (int e = 0; e < N_EXPERTS; ++e) {
                const vfloat4 wv = w_lds_v[e * (HIDDEN / 4) + idx];
                accA[e] += va.x * wv.x + va.y * wv.y + va.z * wv.z + va.w * wv.w;
                accB[e] += vb.x * wv.x + vb.y * wv.y + vb.z * wv.z + vb.w * wv.w;
            }
        }

        // Wave-wide butterfly reduction (64 lanes) for all 10 logits
        #pragma unroll
        for (int e = 0; e < N_EXPERTS; ++e) {
            float va = accA[e];
            float vb = accB[e];
            #pragma unroll
            for (int off = 32; off > 0; off >>= 1) {
                va += __shfl_xor(va, off, 64);
                vb += __shfl_xor(vb, off, 64);
            }
            accA[e] = va;
            accB[e] = vb;
        }

        if (lane == 0) {
            float w0[2], w1[2];
            float idx0[2], idx1[2];
            const float* logits_arr[2] = {accA, accB};
            #pragma unroll
            for (int t = 0; t < 2; ++t) {
                const float* logits = logits_arr[t];
                // top-1: strict > keeps lowest index on ties (lax.top_k stable order)
                int i1 = 0;
                float m1 = logits[0];
                #pragma unroll
                for (int e = 1; e < N_EXPERTS; ++e) {
                    if (logits[e] > m1) { m1 = logits[e]; i1 = e; }
                }
                // top-2: first (lowest-index) max among the rest
                int i2 = -1;
                float m2 = -INFINITY;
                #pragma unroll
                for (int e = 0; e < N_EXPERTS; ++e) {
                    if (e != i1 && logits[e] > m2) { m2 = logits[e]; i2 = e; }
                }
                // normalized top-2 softmax weights: full denom cancels
                const float r = expf(m2 - m1);          // <= 1
                const float inv = 1.0f / (1.0f + r);
                w0[t] = inv;
                w1[t] = r * inv;
                idx0[t] = (float)i1;
                idx1[t] = (float)i2;
            }

            if (hasB) {
                // tokens 2p, 2p+1 -> out_w[4p..4p+3] is one aligned float4
                vfloat4 wv4 = {w0[0], w1[0], w0[1], w1[1]};
                vfloat4 iv4 = {idx0[0], idx1[0], idx0[1], idx1[1]};
                ((vfloat4*)out_w)[p] = wv4;
                ((vfloat4*)out_i)[p] = iv4;
            } else {
                out_w[(size_t)tokA * 2 + 0] = w0[0];
                out_w[(size_t)tokA * 2 + 1] = w1[0];
                out_i[(size_t)tokA * 2 + 0] = idx0[0];
                out_i[(size_t)tokA * 2 + 1] = idx1[0];
            }
        }
    }
}

extern "C" void kernel_launch(void* const* d_in, const int* in_sizes, int n_in,
                              void* d_out, int out_size, void* d_ws, size_t ws_size,
                              hipStream_t stream) {
    const float* x = (const float*)d_in[0];   // [8,4096,2048] fp32
    const float* W = (const float*)d_in[1];   // [5,2048] fp32

    const int n_tokens = in_sizes[0] / HIDDEN;              // 32768

    float* out = (float*)d_out;
    float* out_w   = out;                                    // [N,2]
    float* out_i   = out + (size_t)n_tokens * TOP_K;         // [N,2]
    float* out_tok = out + (size_t)n_tokens * TOP_K * 2;     // [N,HIDDEN]

    // Gate: 1024 blocks x 4 waves = 4096 waves, 4 token-pairs each.
    dim3 grid(1024);
    dim3 block(256);
    moe_gate_kernel<<<grid, block, 0, stream>>>(x, W, out_w, out_i, n_tokens);

    // Token copy via ROCm blit path (no write-allocate RMW; ~6.3 TB/s).
    hipMemcpyAsync(out_tok, x, (size_t)n_tokens * HIDDEN * sizeof(float),
                   hipMemcpyDeviceToDevice, stream);
}